// Round 4
// baseline (219.372 us; speedup 1.0000x reference)
//
#include <hip/hip_runtime.h>
#include <hip/hip_bf16.h>
#include <math.h>

// Problem constants (fixed by setup_inputs)
#define CIN      8
#define H_IN     100
#define W_IN     136
#define NPIX     (H_IN * W_IN)       // 13600
#define OH       (2 * H_IN)          // 200
#define OW       (2 * W_IN)          // 272
#define ONPIX    (OH * OW)           // 54400
#define NPARAMS  169
#define EPSV     1e-5f
#define NSLICE   4                   // row-slices per instance
#define KGROUPS  34                  // 272/8 col-groups
#define TASKS    (25 * KGROUPS)      // 850 tasks per slice
#define NITER_A  7                   // ceil(26*136 / 512)

// param layout: w0[8][10] @0, w1[8][8] @80, w2[8] @144, b0 @152, b1 @160, b2 @168

__device__ __forceinline__ float sigmoidf_fast(float x) {
    float e = __expf(-x);
    return __builtin_amdgcn_rcpf(1.f + e);
}

// Register model (this session's measurements): ~256 VGPR/SIMD effective pool.
// 112 regs -> 2 waves/SIMD (20% occ, rounds 1/3); forcing 64 via (256,4) on
// 112-natural code spilled 1.8 GB (round 2). Fix: make the code NATURALLY
// small (2 px/thread, weights via scalar loads) and cap loosely at (256,3).
__global__ __launch_bounds__(256, 3)
void mask_head_fused(const float* __restrict__ mask_feats,   // [N,8,100,136]
                     const float* __restrict__ params,       // [n,169]
                     const float* __restrict__ locs,         // [n,2]
                     const float* __restrict__ gt,           // [n,1,200,272]
                     const int*   __restrict__ im_inds,      // [n]
                     const int*   __restrict__ fpn_levels,   // [n]
                     float*       __restrict__ partials)     // [n*4][3]
{
    const int inst  = blockIdx.x >> 2;
    const int slice = blockIdx.x & 3;
    const int tid   = threadIdx.x;

    // src rows for this slice: max(25*slice-1,0) .. 25*slice+24
    const int r_start = (slice == 0) ? 0 : 25 * slice - 1;
    const int nrows   = (slice == 0) ? 25 : 26;
    const int npx     = nrows * W_IN;              // <= 3536

    __shared__ float s_logit[26 * W_IN];           // 14144 B
    __shared__ float s_red[12];

    // Block-uniform weight pointer -> compiler scalarizes these loads (s_load,
    // scalar K$): zero VALU/LDS cost for weights, no staging barrier.
    const float* __restrict__ wp = params + (size_t)inst * NPARAMS;

    const int   im  = im_inds[inst];
    const int   lvl = fpn_levels[inst];
    const float inv_soi = exp2f(-(float)(3 + lvl));  // SOI = 8*2^lvl, exact
    const float lx = locs[inst * 2 + 0];
    const float ly = locs[inst * 2 + 1];

    const float* feat = mask_feats + (size_t)im * (CIN * NPIX);
    const int goff = r_start * W_IN;   // global pixel offset of local pixel 0

    // ---------------- Phase A: logits for this slice's src rows -> LDS ----------------
    // 2 px/thread/iter keeps live VGPRs ~50 -> 3-4 waves/SIMD resident.
    #pragma unroll 1
    for (int it = 0; it < NITER_A; ++it) {
        const int p0 = it * 512 + tid;
        const int p1 = p0 + 256;
        const int pc0 = p0 < npx ? p0 : npx - 1;
        const int pc1 = p1 < npx ? p1 : npx - 1;
        const int r0 = pc0 / W_IN;
        const int x0 = pc0 - r0 * W_IN;
        const int r1 = pc1 / W_IN;
        const int x1 = pc1 - r1 * W_IN;

        float in[10][2];
        in[0][0] = (lx - (float)(x0 * 8 + 4)) * inv_soi;
        in[1][0] = (ly - (float)((r_start + r0) * 8 + 4)) * inv_soi;
        in[0][1] = (lx - (float)(x1 * 8 + 4)) * inv_soi;
        in[1][1] = (ly - (float)((r_start + r1) * 8 + 4)) * inv_soi;
        const int g0 = goff + pc0;
        const int g1 = goff + pc1;
        #pragma unroll
        for (int c = 0; c < CIN; ++c) {
            in[2 + c][0] = feat[c * NPIX + g0];
            in[2 + c][1] = feat[c * NPIX + g1];
        }

        // layer 0: 10 -> 8, relu
        float h0[8][2];
        #pragma unroll
        for (int o = 0; o < 8; ++o) {
            const float b = wp[152 + o];
            float a0 = b, a1 = b;
            #pragma unroll
            for (int i = 0; i < 10; ++i) {
                const float w = wp[o * 10 + i];
                a0 = fmaf(w, in[i][0], a0);
                a1 = fmaf(w, in[i][1], a1);
            }
            h0[o][0] = fmaxf(a0, 0.f);
            h0[o][1] = fmaxf(a1, 0.f);
        }

        // layer 1: 8 -> 8, relu
        float h1[8][2];
        #pragma unroll
        for (int o = 0; o < 8; ++o) {
            const float b = wp[160 + o];
            float a0 = b, a1 = b;
            #pragma unroll
            for (int i = 0; i < 8; ++i) {
                const float w = wp[80 + o * 8 + i];
                a0 = fmaf(w, h0[i][0], a0);
                a1 = fmaf(w, h0[i][1], a1);
            }
            h1[o][0] = fmaxf(a0, 0.f);
            h1[o][1] = fmaxf(a1, 0.f);
        }

        // layer 2: 8 -> 1
        const float b2 = wp[168];
        float o0 = b2, o1 = b2;
        #pragma unroll
        for (int i = 0; i < 8; ++i) {
            const float w = wp[144 + i];
            o0 = fmaf(w, h1[i][0], o0);
            o1 = fmaf(w, h1[i][1], o1);
        }
        if (p0 < npx) s_logit[p0] = o0;
        if (p1 < npx) s_logit[p1] = o1;
    }

    __syncthreads();

    // ---------------- Phase B: structured x2 upsample + sigmoid + dice ----------------
    // Output row 2p   = avg(src row p-1, src row p)   (p=0: src row 0)
    // Output row 2p+1 = src row p
    // Output cols: o[2j]=avg of adjacent src cols, o[2j+1]=src col (left edge clamped)
    float inter = 0.f, ssum = 0.f, tsum = 0.f;
    const float* gtp = gt + (size_t)inst * ONPIX;
    const int pair_base = 25 * slice;

    #pragma unroll 1
    for (int base = 0; base < TASKS; base += 256) {
        const int task = base + tid;
        if (task < TASKS) {
            const int pl = task / KGROUPS;
            const int k  = task - pl * KGROUPS;
            const int pg = pair_base + pl;
            const int er = pg - r_start;                       // exact src row (local)
            const int pr = (pg > 0 ? pg - 1 : 0) - r_start;    // prev src row (local)
            const float* E = s_logit + er * W_IN;
            const float* P = s_logit + pr * W_IN;
            const int c0  = 4 * k;
            const int cm1 = (k > 0) ? c0 - 1 : 0;

            const float4 e4 = *(const float4*)(E + c0);
            const float  em = E[cm1];
            const float4 p4 = *(const float4*)(P + c0);
            const float  pm = P[cm1];

            const float* g0 = gtp + (size_t)(2 * pg) * OW + 8 * k;
            const float4 ga = *(const float4*)(g0);            // avg row, cols 0-3
            const float4 gb = *(const float4*)(g0 + 4);        // avg row, cols 4-7
            const float4 gc = *(const float4*)(g0 + OW);       // exact row, cols 0-3
            const float4 gd = *(const float4*)(g0 + OW + 4);   // exact row, cols 4-7

            const float ecur[4] = {e4.x, e4.y, e4.z, e4.w};
            const float pcur[4] = {p4.x, p4.y, p4.z, p4.w};
            const float gav[8]  = {ga.x, ga.y, ga.z, ga.w, gb.x, gb.y, gb.z, gb.w};
            const float gex[8]  = {gc.x, gc.y, gc.z, gc.w, gd.x, gd.y, gd.z, gd.w};

            float Se_prev = em;
            float Sa_prev = 0.5f * (em + pm);
            #pragma unroll
            for (int j = 0; j < 4; ++j) {
                const float Se = ecur[j];
                const float Sa = 0.5f * (ecur[j] + pcur[j]);
                // avg row: col 2j (avg), col 2j+1 (exact col)
                {
                    float s = sigmoidf_fast(0.5f * (Sa_prev + Sa));
                    float t = gav[2 * j];
                    inter = fmaf(s, t, inter); ssum = fmaf(s, s, ssum); tsum = fmaf(t, t, tsum);
                    s = sigmoidf_fast(Sa);
                    t = gav[2 * j + 1];
                    inter = fmaf(s, t, inter); ssum = fmaf(s, s, ssum); tsum = fmaf(t, t, tsum);
                }
                // exact row
                {
                    float s = sigmoidf_fast(0.5f * (Se_prev + Se));
                    float t = gex[2 * j];
                    inter = fmaf(s, t, inter); ssum = fmaf(s, s, ssum); tsum = fmaf(t, t, tsum);
                    s = sigmoidf_fast(Se);
                    t = gex[2 * j + 1];
                    inter = fmaf(s, t, inter); ssum = fmaf(s, s, ssum); tsum = fmaf(t, t, tsum);
                }
                Se_prev = Se;
                Sa_prev = Sa;
            }
        }
    }

    // block reduction (4 waves of 64)
    #pragma unroll
    for (int off = 32; off > 0; off >>= 1) {
        inter += __shfl_down(inter, off, 64);
        ssum  += __shfl_down(ssum,  off, 64);
        tsum  += __shfl_down(tsum,  off, 64);
    }
    const int wid = tid >> 6;
    if ((tid & 63) == 0) {
        s_red[wid * 3 + 0] = inter;
        s_red[wid * 3 + 1] = ssum;
        s_red[wid * 3 + 2] = tsum;
    }
    __syncthreads();
    if (tid == 0) {
        float I = 0.f, S = 0.f, T = 0.f;
        #pragma unroll
        for (int w = 0; w < 4; ++w) {
            I += s_red[w * 3 + 0];
            S += s_red[w * 3 + 1];
            T += s_red[w * 3 + 2];
        }
        partials[blockIdx.x * 3 + 0] = I;
        partials[blockIdx.x * 3 + 1] = S;
        partials[blockIdx.x * 3 + 2] = T;
    }
}

__global__ __launch_bounds__(512)
void loss_mean_kernel(const float* __restrict__ partials, float* __restrict__ out, int n)
{
    __shared__ float s_red[8];
    float v = 0.f;
    for (int i = threadIdx.x; i < n; i += 512) {
        float I = 0.f, S = 0.f, T = 0.f;
        #pragma unroll
        for (int s = 0; s < NSLICE; ++s) {
            const float* p = partials + (size_t)(i * NSLICE + s) * 3;
            I += p[0];
            S += p[1];
            T += p[2];
        }
        v += 1.f - 2.f * I / (S + T + EPSV);
    }
    #pragma unroll
    for (int off = 32; off > 0; off >>= 1) v += __shfl_down(v, off, 64);
    const int wid = threadIdx.x >> 6;
    if ((threadIdx.x & 63) == 0) s_red[wid] = v;
    __syncthreads();
    if (threadIdx.x == 0) {
        float s = 0.f;
        #pragma unroll
        for (int w = 0; w < 8; ++w) s += s_red[w];
        out[0] = s / (float)n;
    }
}

extern "C" void kernel_launch(void* const* d_in, const int* in_sizes, int n_in,
                              void* d_out, int out_size, void* d_ws, size_t ws_size,
                              hipStream_t stream)
{
    const float* mask_feats = (const float*)d_in[0];
    const float* params     = (const float*)d_in[1];
    const float* locs       = (const float*)d_in[2];
    const float* gt         = (const float*)d_in[3];
    const int*   im_inds    = (const int*)d_in[4];
    const int*   fpn_levels = (const int*)d_in[5];
    // d_in[6] = mask_feat_stride (always 8 for this problem)

    const int n = in_sizes[4];          // 500 instances
    float* partials = (float*)d_ws;     // n*NSLICE*3 floats

    mask_head_fused<<<n * NSLICE, 256, 0, stream>>>(mask_feats, params, locs, gt,
                                                    im_inds, fpn_levels, partials);
    loss_mean_kernel<<<1, 512, 0, stream>>>(partials, (float*)d_out, n);
}

// Round 5
// 182.822 us; speedup vs baseline: 1.1999x; 1.1999x over previous
//
#include <hip/hip_runtime.h>
#include <hip/hip_bf16.h>
#include <math.h>

// Problem constants (fixed by setup_inputs)
#define CIN      8
#define H_IN     100
#define W_IN     136
#define NPIX     (H_IN * W_IN)       // 13600
#define OH       (2 * H_IN)          // 200
#define OW       (2 * W_IN)          // 272
#define ONPIX    (OH * OW)           // 54400
#define NPARAMS  169
#define EPSV     1e-5f
#define NSLICE   4                   // row-slices per instance
#define KG4      34                  // 136/4 col-groups of 4 src px
#define KGROUPS  34                  // 272/8 output col-groups
#define TASKS_B  (25 * KGROUPS)      // 850 phase-B tasks per slice

// param layout: w0[8][10] @0, w1[8][8] @80, w2[8] @144, b0 @152, b1 @160, b2 @168

__device__ __forceinline__ float sigmoidf_fast(float x) {
    float e = __expf(-x);
    return __builtin_amdgcn_rcpf(1.f + e);
}

// Session resource model: (256,4) cap=64 on fat code -> 1.8GB spill (R2).
// (256,3) cap=85 -> compiler collapsed to VGPR=28, serializing feat loads (R4).
// Here: code is naturally ~90-100 VGPR with wide upfront loads; cap loosely at
// (256,2)=128 so the allocator keeps the ILP schedule. Occupancy 20% is fine —
// R3->R4 proved occupancy is not the limiter; instruction/pipe work is.
__global__ __launch_bounds__(256, 2)
void mask_head_fused(const float* __restrict__ mask_feats,   // [N,8,100,136]
                     const float* __restrict__ params,       // [n,169]
                     const float* __restrict__ locs,         // [n,2]
                     const float* __restrict__ gt,           // [n,1,200,272]
                     const int*   __restrict__ im_inds,      // [n]
                     const int*   __restrict__ fpn_levels,   // [n]
                     float*       __restrict__ partials)     // [n*4][3]
{
    const int inst  = blockIdx.x >> 2;
    const int slice = blockIdx.x & 3;
    const int tid   = threadIdx.x;

    // src rows for this slice: max(25*slice-1,0) .. 25*slice+24
    const int r_start = (slice == 0) ? 0 : 25 * slice - 1;
    const int nrows   = (slice == 0) ? 25 : 26;
    const int ntask   = nrows * KG4;               // <= 884

    __shared__ float s_logit[26 * W_IN];           // 14144 B
    __shared__ float s_red[12];

    // Block-uniform weight pointer -> scalar K$ loads (s_load), zero VALU/LDS
    // cost for weights (R4 evidence: SGPR_Count=112, weights scalarized).
    const float* __restrict__ wp = params + (size_t)inst * NPARAMS;

    const int   im  = im_inds[inst];
    const int   lvl = fpn_levels[inst];
    const float inv_soi = exp2f(-(float)(3 + lvl));  // SOI = 8*2^lvl, exact
    const float lx = locs[inst * 2 + 0];
    const float ly = locs[inst * 2 + 1];
    const float dx8 = 8.f * inv_soi;

    const float* feat = mask_feats + (size_t)im * (CIN * NPIX);
    const int goff = r_start * W_IN;   // global pixel offset of local row 0

    // ---------------- Phase A: logits for this slice's src rows -> LDS ----------
    // Task = 4 consecutive px in ONE row (row r, cols 4k..4k+3).
    // 8 x global_load_dwordx4 per task (2 wide loads/px), weights on scalar pipe,
    // one division per 4 px, one ds_write_b128 per task.
    #pragma unroll 1
    for (int it = 0; it < 4; ++it) {
        const int t = it * 256 + tid;
        const bool valid = t < ntask;
        const int tc = valid ? t : ntask - 1;
        const int r  = tc / KG4;                   // local row (magic div)
        const int k  = tc - r * KG4;
        const int lpx = r * W_IN + 4 * k;          // local px of first of 4
        const float* fb = feat + (goff + lpx);

        // 8 independent 16B loads, issued upfront
        float4 f0 = *(const float4*)(fb);
        float4 f1 = *(const float4*)(fb + NPIX);
        float4 f2 = *(const float4*)(fb + 2 * NPIX);
        float4 f3 = *(const float4*)(fb + 3 * NPIX);
        float4 f4 = *(const float4*)(fb + 4 * NPIX);
        float4 f5 = *(const float4*)(fb + 5 * NPIX);
        float4 f6 = *(const float4*)(fb + 6 * NPIX);
        float4 f7 = *(const float4*)(fb + 7 * NPIX);

        // rel-coord inputs: in0 varies across the 4 px, in1 row-uniform
        float in0[4];
        in0[0] = (lx - (float)(32 * k + 4)) * inv_soi;
        in0[1] = in0[0] - dx8;
        in0[2] = in0[1] - dx8;
        in0[3] = in0[2] - dx8;
        const float in1 = (ly - (float)((r_start + r) * 8 + 4)) * inv_soi;

        // layer 0: 10 -> 8 (rel coords first, then stream channels)
        float a[8][4];
        #pragma unroll
        for (int o = 0; o < 8; ++o) {
            const float b  = wp[152 + o];
            const float w0 = wp[o * 10 + 0];
            const float w1 = wp[o * 10 + 1];
            const float base = fmaf(w1, in1, b);
            #pragma unroll
            for (int j = 0; j < 4; ++j)
                a[o][j] = fmaf(w0, in0[j], base);
        }
        const float* fc[8][1];
        float f[8][4];
        f[0][0]=f0.x; f[0][1]=f0.y; f[0][2]=f0.z; f[0][3]=f0.w;
        f[1][0]=f1.x; f[1][1]=f1.y; f[1][2]=f1.z; f[1][3]=f1.w;
        f[2][0]=f2.x; f[2][1]=f2.y; f[2][2]=f2.z; f[2][3]=f2.w;
        f[3][0]=f3.x; f[3][1]=f3.y; f[3][2]=f3.z; f[3][3]=f3.w;
        f[4][0]=f4.x; f[4][1]=f4.y; f[4][2]=f4.z; f[4][3]=f4.w;
        f[5][0]=f5.x; f[5][1]=f5.y; f[5][2]=f5.z; f[5][3]=f5.w;
        f[6][0]=f6.x; f[6][1]=f6.y; f[6][2]=f6.z; f[6][3]=f6.w;
        f[7][0]=f7.x; f[7][1]=f7.y; f[7][2]=f7.z; f[7][3]=f7.w;
        (void)fc;
        #pragma unroll
        for (int c = 0; c < CIN; ++c) {
            #pragma unroll
            for (int o = 0; o < 8; ++o) {
                const float w = wp[o * 10 + 2 + c];
                a[o][0] = fmaf(w, f[c][0], a[o][0]);
                a[o][1] = fmaf(w, f[c][1], a[o][1]);
                a[o][2] = fmaf(w, f[c][2], a[o][2]);
                a[o][3] = fmaf(w, f[c][3], a[o][3]);
            }
        }
        #pragma unroll
        for (int o = 0; o < 8; ++o) {
            a[o][0] = fmaxf(a[o][0], 0.f);
            a[o][1] = fmaxf(a[o][1], 0.f);
            a[o][2] = fmaxf(a[o][2], 0.f);
            a[o][3] = fmaxf(a[o][3], 0.f);
        }

        // layer 1: 8 -> 8, relu
        float h[8][4];
        #pragma unroll
        for (int o = 0; o < 8; ++o) {
            const float b = wp[160 + o];
            h[o][0] = b; h[o][1] = b; h[o][2] = b; h[o][3] = b;
        }
        #pragma unroll
        for (int i = 0; i < 8; ++i) {
            #pragma unroll
            for (int o = 0; o < 8; ++o) {
                const float w = wp[80 + o * 8 + i];
                h[o][0] = fmaf(w, a[i][0], h[o][0]);
                h[o][1] = fmaf(w, a[i][1], h[o][1]);
                h[o][2] = fmaf(w, a[i][2], h[o][2]);
                h[o][3] = fmaf(w, a[i][3], h[o][3]);
            }
        }

        // layer 2: 8 -> 1 (relu folded: max on h inputs)
        const float b2 = wp[168];
        float o4[4] = {b2, b2, b2, b2};
        #pragma unroll
        for (int i = 0; i < 8; ++i) {
            const float w = wp[144 + i];
            o4[0] = fmaf(w, fmaxf(h[i][0], 0.f), o4[0]);
            o4[1] = fmaf(w, fmaxf(h[i][1], 0.f), o4[1]);
            o4[2] = fmaf(w, fmaxf(h[i][2], 0.f), o4[2]);
            o4[3] = fmaf(w, fmaxf(h[i][3], 0.f), o4[3]);
        }

        if (valid) {
            float4 ov = {o4[0], o4[1], o4[2], o4[3]};
            *(float4*)(s_logit + lpx) = ov;   // 16B-aligned: (r*136+4k)*4
        }
    }

    __syncthreads();

    // ---------------- Phase B: structured x2 upsample + sigmoid + dice ----------
    // Output row 2p   = avg(src row p-1, src row p)   (p=0: src row 0)
    // Output row 2p+1 = src row p
    // Output cols: o[2j]=avg of adjacent src cols, o[2j+1]=src col (left edge clamp)
    float inter = 0.f, ssum = 0.f, tsum = 0.f;
    const float* gtp = gt + (size_t)inst * ONPIX;
    const int pair_base = 25 * slice;

    #pragma unroll 1
    for (int base = 0; base < TASKS_B; base += 256) {
        const int task = base + tid;
        if (task < TASKS_B) {
            const int pl = task / KGROUPS;
            const int k  = task - pl * KGROUPS;
            const int pg = pair_base + pl;
            const int er = pg - r_start;                       // exact src row (local)
            const int pr = (pg > 0 ? pg - 1 : 0) - r_start;    // prev src row (local)
            const float* E = s_logit + er * W_IN;
            const float* P = s_logit + pr * W_IN;
            const int c0  = 4 * k;
            const int cm1 = (k > 0) ? c0 - 1 : 0;

            const float4 e4 = *(const float4*)(E + c0);
            const float  em = E[cm1];
            const float4 p4 = *(const float4*)(P + c0);
            const float  pm = P[cm1];

            const float* g0 = gtp + (size_t)(2 * pg) * OW + 8 * k;
            const float4 ga = *(const float4*)(g0);            // avg row, cols 0-3
            const float4 gb = *(const float4*)(g0 + 4);        // avg row, cols 4-7
            const float4 gc = *(const float4*)(g0 + OW);       // exact row, cols 0-3
            const float4 gd = *(const float4*)(g0 + OW + 4);   // exact row, cols 4-7

            const float ecur[4] = {e4.x, e4.y, e4.z, e4.w};
            const float pcur[4] = {p4.x, p4.y, p4.z, p4.w};
            const float gav[8]  = {ga.x, ga.y, ga.z, ga.w, gb.x, gb.y, gb.z, gb.w};
            const float gex[8]  = {gc.x, gc.y, gc.z, gc.w, gd.x, gd.y, gd.z, gd.w};

            float Se_prev = em;
            float Sa_prev = 0.5f * (em + pm);
            #pragma unroll
            for (int j = 0; j < 4; ++j) {
                const float Se = ecur[j];
                const float Sa = 0.5f * (ecur[j] + pcur[j]);
                {
                    float s = sigmoidf_fast(0.5f * (Sa_prev + Sa));
                    float t = gav[2 * j];
                    inter = fmaf(s, t, inter); ssum = fmaf(s, s, ssum); tsum = fmaf(t, t, tsum);
                    s = sigmoidf_fast(Sa);
                    t = gav[2 * j + 1];
                    inter = fmaf(s, t, inter); ssum = fmaf(s, s, ssum); tsum = fmaf(t, t, tsum);
                }
                {
                    float s = sigmoidf_fast(0.5f * (Se_prev + Se));
                    float t = gex[2 * j];
                    inter = fmaf(s, t, inter); ssum = fmaf(s, s, ssum); tsum = fmaf(t, t, tsum);
                    s = sigmoidf_fast(Se);
                    t = gex[2 * j + 1];
                    inter = fmaf(s, t, inter); ssum = fmaf(s, s, ssum); tsum = fmaf(t, t, tsum);
                }
                Se_prev = Se;
                Sa_prev = Sa;
            }
        }
    }

    // block reduction (4 waves of 64)
    #pragma unroll
    for (int off = 32; off > 0; off >>= 1) {
        inter += __shfl_down(inter, off, 64);
        ssum  += __shfl_down(ssum,  off, 64);
        tsum  += __shfl_down(tsum,  off, 64);
    }
    const int wid = tid >> 6;
    if ((tid & 63) == 0) {
        s_red[wid * 3 + 0] = inter;
        s_red[wid * 3 + 1] = ssum;
        s_red[wid * 3 + 2] = tsum;
    }
    __syncthreads();
    if (tid == 0) {
        float I = 0.f, S = 0.f, T = 0.f;
        #pragma unroll
        for (int w = 0; w < 4; ++w) {
            I += s_red[w * 3 + 0];
            S += s_red[w * 3 + 1];
            T += s_red[w * 3 + 2];
        }
        partials[blockIdx.x * 3 + 0] = I;
        partials[blockIdx.x * 3 + 1] = S;
        partials[blockIdx.x * 3 + 2] = T;
    }
}

__global__ __launch_bounds__(512)
void loss_mean_kernel(const float* __restrict__ partials, float* __restrict__ out, int n)
{
    __shared__ float s_red[8];
    float v = 0.f;
    for (int i = threadIdx.x; i < n; i += 512) {
        float I = 0.f, S = 0.f, T = 0.f;
        #pragma unroll
        for (int s = 0; s < NSLICE; ++s) {
            const float* p = partials + (size_t)(i * NSLICE + s) * 3;
            I += p[0];
            S += p[1];
            T += p[2];
        }
        v += 1.f - 2.f * I / (S + T + EPSV);
    }
    #pragma unroll
    for (int off = 32; off > 0; off >>= 1) v += __shfl_down(v, off, 64);
    const int wid = threadIdx.x >> 6;
    if ((threadIdx.x & 63) == 0) s_red[wid] = v;
    __syncthreads();
    if (threadIdx.x == 0) {
        float s = 0.f;
        #pragma unroll
        for (int w = 0; w < 8; ++w) s += s_red[w];
        out[0] = s / (float)n;
    }
}

extern "C" void kernel_launch(void* const* d_in, const int* in_sizes, int n_in,
                              void* d_out, int out_size, void* d_ws, size_t ws_size,
                              hipStream_t stream)
{
    const float* mask_feats = (const float*)d_in[0];
    const float* params     = (const float*)d_in[1];
    const float* locs       = (const float*)d_in[2];
    const float* gt         = (const float*)d_in[3];
    const int*   im_inds    = (const int*)d_in[4];
    const int*   fpn_levels = (const int*)d_in[5];
    // d_in[6] = mask_feat_stride (always 8 for this problem)

    const int n = in_sizes[4];          // 500 instances
    float* partials = (float*)d_ws;     // n*NSLICE*3 floats

    mask_head_fused<<<n * NSLICE, 256, 0, stream>>>(mask_feats, params, locs, gt,
                                                    im_inds, fpn_levels, partials);
    loss_mean_kernel<<<1, 512, 0, stream>>>(partials, (float*)d_out, n);
}